// Round 7
// baseline (131.858 us; speedup 1.0000x reference)
//
#include <hip/hip_runtime.h>

#define B_ 16
#define A_ 3
#define G_ 76
#define GG_ (G_*G_)             // 5776
#define NC_ 80
#define C_ 85
#define NCELL (B_*A_*GG_)       // 277248
#define NBLK2 (NCELL/256)       // 1083 loss blocks
#define OUTN ((size_t)NCELL*C_) // 23566080
#define NF4 (OUTN/4)            // 5891520 output float4s
#define K1_GRID ((NF4 + 255)/256) // 23014

typedef float f4 __attribute__((ext_vector_type(4)));

__device__ __forceinline__ float sigf(float v){ return 1.0f/(1.0f + __expf(-v)); }
__device__ __forceinline__ float clog_(float p){ return fmaxf(__logf(p), -100.0f); }
__device__ __forceinline__ float bcef(float p, float t){ return -(t*clog_(p) + (1.0f-t)*clog_(1.0f-p)); }

// ---------------- mask dtype detection (scans dense noobj mask head) ----------------
__global__ __launch_bounds__(256) void detect_kernel(const unsigned int* __restrict__ nm,
                                                     unsigned int* __restrict__ flags){
    unsigned idx = blockIdx.x*256u + threadIdx.x;
    unsigned v = (idx < 4096u) ? nm[idx] : 0u;
    unsigned a01 = (v > 1u) ? 1u : 0u;                            // not int32 {0,1}
    unsigned afl = ((v != 0u) && (v != 0x3F800000u)) ? 1u : 0u;   // not f32 {0,1.0}
    if (__any(a01) && (threadIdx.x & 63) == 0) atomicOr(&flags[0], 1u);
    if (__any(afl) && (threadIdx.x & 63) == 0) atomicOr(&flags[1], 1u);
}

// ---------------- K1: output-driven gather transform (no LDS, no barriers) ----------------
__global__ __launch_bounds__(256) void transform_kernel(const float* __restrict__ x,
                                                        float* __restrict__ out){
    // bijective XCD-chunked swizzle (nwg % 8 != 0)
    unsigned nwg = gridDim.x;
    unsigned q = nwg >> 3, r = nwg & 7u;
    unsigned xcd = blockIdx.x & 7u, seq = blockIdx.x >> 3;
    unsigned blk = (xcd < r ? xcd*(q+1u) : r*(q+1u) + (xcd-r)*q) + seq;

    int o = (int)(blk*256u + threadIdx.x);        // output float4 index
    if (o >= (int)NF4) return;
    int e0 = o*4;                                  // output element index
    int c  = e0/C_;                                // global cell
    int k  = e0 - c*C_;
    int ba = c/GG_;
    int ij = c - ba*GG_;
    int a  = ba % A_;
    int in_ = ij/G_;
    int jn  = ij - in_*G_;

    f4 rv;
    #pragma unroll
    for (int t=0;t<4;t++){
        float v = x[(size_t)(ba*C_ + k)*GG_ + ij];
        float r_;
        if (k >= 4)      r_ = sigf(v);
        else if (k == 0) r_ = (sigf(v) + (float)jn)*8.0f;
        else if (k == 1) r_ = (sigf(v) + (float)in_)*8.0f;
        else if (k == 2) r_ = __expf(v)*((a==0)?12.0f:((a==1)?19.0f:40.0f));
        else             r_ = __expf(v)*((a==0)?16.0f:((a==1)?36.0f:28.0f));
        rv[t] = r_;
        // advance one element
        k++;
        if (k == C_){
            k = 0; ij++; jn++;
            if (jn == G_){ jn = 0; in_++; }
            if (ij == GG_){ ij = 0; jn = 0; in_ = 0; ba++; a = (a==2)?0:(a+1); }
        }
    }
    *(f4*)(out + (size_t)o*4) = rv;
}

// ---------------- K2: loss (reads x directly; one thread per cell) ----------------
__global__ __launch_bounds__(256) void loss_kernel(
        const float* __restrict__ x, const float* __restrict__ iou,
        const void* __restrict__ om, const void* __restrict__ nm,
        const float* __restrict__ tw, const float* __restrict__ th,
        const float* __restrict__ tcls, const float* __restrict__ tconf,
        const float* __restrict__ tbox, const unsigned int* __restrict__ flags,
        float* __restrict__ partials){
    int n = blockIdx.x*256 + threadIdx.x;          // grid sized exactly
    int mode = (flags[0]==0u) ? 0 : ((flags[1]==0u) ? 1 : 2);
    bool obj, noobj;
    if (mode == 2){
        obj   = ((const unsigned char*)om)[n] != 0;
        noobj = ((const unsigned char*)nm)[n] != 0;
    } else {
        obj   = ((const unsigned int*)om)[n] != 0u;   // int32 {0,1} or f32 {0,1.0f}
        noobj = ((const unsigned int*)nm)[n] != 0u;
    }

    float s0=0.f, s1=0.f, s2=0.f, s3=0.f;
    if (obj || noobj){
        int ba = n / GG_;
        int ij = n - ba*GG_;
        const float* xc = x + (size_t)(ba*C_)*GG_ + ij;
        float pconf = sigf(xc[(size_t)4*GG_]);
        float bc = bcef(pconf, tconf[n]);
        if (noobj) s2 = bc;
        if (obj){
            s1 = bc;
            int a = ba % A_;
            int in_ = ij/G_;
            int jn  = ij - in_*G_;
            float aw = (a==0)?1.5f:((a==1)?2.375f:5.0f);
            float ah = (a==0)?2.0f:((a==1)?4.5f:3.5f);
            float pxv = sigf(xc[0]);
            float pyv = sigf(xc[(size_t)GG_]);
            float pwv = xc[(size_t)2*GG_];
            float phv = xc[(size_t)3*GG_];
            float bx = pxv + (float)jn;
            float by = pyv + (float)in_;
            float bw = __expf(pwv)*aw;
            float bh = __expf(phv)*ah;
            f4 tb = *(const f4*)(tbox + (size_t)n*4);
            float txc=tb[0], tyc=tb[1], twd=tb[2], tht=tb[3];
            float tx1 = txc - twd*0.5f, ty1 = tyc - tht*0.5f;
            float tx2 = txc + twd*0.5f, ty2 = tyc + tht*0.5f;
            float px1 = bx - bw*0.5f,  py1 = by - bh*0.5f;
            float px2 = bx + bw*0.5f,  py2 = by + bh*0.5f;
            float xc1 = fminf(px1, tx1), yc1 = fminf(py1, ty1);
            float xc2 = fmaxf(px2, tx2), yc2 = fmaxf(py2, ty2);
            float cc = (xc2-xc1)*(xc2-xc1) + (yc2-yc1)*(yc2-yc1) + 1e-7f;
            float dd = (txc-bx)*(txc-bx) + (tyc-by)*(tyc-by);
            float rdiou = dd/cc;
            float dat = atanf(tw[n]/th[n]) - atanf(pwv/phv);
            float vv = 0.40528473456935108577f * dat*dat;
            float Si = 1.0f - iou[n];
            float alpha = vv/(Si+vv);
            s0 = 1.0f - iou[n] + rdiou + alpha*vv;
            const float* tcl = tcls + (size_t)n*NC_;
            float cls = 0.f;
            #pragma unroll 4
            for (int cdx=0;cdx<NC_;cdx++){
                float p = sigf(xc[(size_t)(5+cdx)*GG_]);
                cls += bcef(p, tcl[cdx]);
            }
            s3 = cls;
        }
    }

    unsigned long long bo  = __ballot(obj);
    unsigned long long bn2 = __ballot(noobj);
    float vals[4] = {s0, s1, s2, s3};
    #pragma unroll
    for (int qq=0;qq<4;qq++){
        float vv2 = vals[qq];
        #pragma unroll
        for (int oo=32;oo>0;oo>>=1) vv2 += __shfl_xor(vv2, oo, 64);
        vals[qq] = vv2;
    }
    __shared__ float sm[6][4];
    int lane = (int)threadIdx.x & 63, wid = (int)threadIdx.x >> 6;
    if (lane == 0){
        sm[0][wid] = vals[0]; sm[1][wid] = vals[1];
        sm[2][wid] = vals[2]; sm[3][wid] = vals[3];
        sm[4][wid] = (float)__popcll(bo);
        sm[5][wid] = (float)__popcll(bn2);
    }
    __syncthreads();
    if (threadIdx.x == 0){
        #pragma unroll
        for (int qq=0;qq<6;qq++)
            partials[(size_t)qq*NBLK2 + blockIdx.x] = sm[qq][0]+sm[qq][1]+sm[qq][2]+sm[qq][3];
    }
}

// ---------------- final reduction ----------------
__global__ __launch_bounds__(256) void final_kernel(const float* __restrict__ partials,
                                                    float* __restrict__ out_loss){
    double acc[6] = {0,0,0,0,0,0};
    for (int idx = (int)threadIdx.x; idx < NBLK2; idx += 256){
        #pragma unroll
        for (int qq=0;qq<6;qq++) acc[qq] += (double)partials[(size_t)qq*NBLK2 + idx];
    }
    #pragma unroll
    for (int qq=0;qq<6;qq++){
        double v = acc[qq];
        #pragma unroll
        for (int oo=32;oo>0;oo>>=1) v += __shfl_xor(v, oo, 64);
        acc[qq] = v;
    }
    __shared__ double smd[6][4];
    int lane = (int)threadIdx.x & 63, wid = (int)threadIdx.x >> 6;
    if (lane == 0){
        #pragma unroll
        for (int qq=0;qq<6;qq++) smd[qq][wid] = acc[qq];
    }
    __syncthreads();
    if (threadIdx.x == 0){
        double s[6];
        #pragma unroll
        for (int qq=0;qq<6;qq++) s[qq] = smd[qq][0]+smd[qq][1]+smd[qq][2]+smd[qq][3];
        double cnt_o = fmax(s[4], 1.0);
        double cnt_n = fmax(s[5], 1.0);
        double total = s[0]/(double)B_
                     + s[1]/cnt_o
                     + 100.0*s[2]/cnt_n
                     + s[3]/(cnt_o*(double)NC_);
        *out_loss = (float)total;
    }
}

extern "C" void kernel_launch(void* const* d_in, const int* in_sizes, int n_in,
                              void* d_out, int out_size, void* d_ws, size_t ws_size,
                              hipStream_t stream){
    const float* x     = (const float*)d_in[0];
    const float* iou   = (const float*)d_in[1];
    const void*  om    = d_in[2];
    const void*  nm    = d_in[3];
    const float* tw    = (const float*)d_in[4];
    const float* th    = (const float*)d_in[5];
    const float* tcls  = (const float*)d_in[6];
    const float* tconf = (const float*)d_in[7];
    const float* tbox  = (const float*)d_in[8];
    float* out = (float*)d_out;

    unsigned int* flags = (unsigned int*)d_ws;
    float* partials = (float*)((char*)d_ws + 64);

    hipMemsetAsync(d_ws, 0, 64, stream);
    detect_kernel<<<16, 256, 0, stream>>>((const unsigned int*)nm, flags);
    transform_kernel<<<K1_GRID, 256, 0, stream>>>(x, out);
    loss_kernel<<<NBLK2, 256, 0, stream>>>(x, iou, om, nm, tw, th, tcls, tconf, tbox,
                                           flags, partials);
    final_kernel<<<1, 256, 0, stream>>>(partials, out + OUTN);
}

// Round 8
// 81.236 us; speedup vs baseline: 1.6231x; 1.6231x over previous
//
#include <hip/hip_runtime.h>

#define B_ 16
#define A_ 3
#define G_ 76
#define GG_ (G_*G_)             // 5776
#define NC_ 80
#define C_ 85
#define NCELL (B_*A_*GG_)       // 277248
#define OUTN ((size_t)NCELL*C_) // 23566080
#define HR_ 152                 // half-rows per (b,a) plane
#define NBLKM (B_*A_*HR_)       // 7296 mega blocks
#define CELLS_PB 38
#define FPB (CELLS_PB*C_)       // 3230 floats per block
#define NU2 (FPB/2)             // 1615 float2 units
#define NITM 13                 // ceil(1615/128)

typedef float f2 __attribute__((ext_vector_type(2)));
typedef float f4 __attribute__((ext_vector_type(4)));

__device__ __forceinline__ float sigf(float v){ return 1.0f/(1.0f + __expf(-v)); }
__device__ __forceinline__ float clog_(float p){ return fmaxf(__logf(p), -100.0f); }
__device__ __forceinline__ float bcef(float p, float t){ return -(t*clog_(p) + (1.0f-t)*clog_(1.0f-p)); }

// ---------------- mask dtype detection (1 block; noobj mask is ~95% dense) ----------------
__global__ __launch_bounds__(256) void detect_kernel(const unsigned int* __restrict__ nm,
                                                     unsigned int* __restrict__ flags){
    unsigned v = nm[threadIdx.x];
    unsigned a01 = (v > 1u) ? 1u : 0u;                            // not int32 {0,1}
    unsigned afl = ((v != 0u) && (v != 0x3F800000u)) ? 1u : 0u;   // not f32 {0,1.0}
    if (__any(a01) && (threadIdx.x & 63) == 0) atomicOr(&flags[0], 1u);
    if (__any(afl) && (threadIdx.x & 63) == 0) atomicOr(&flags[1], 1u);
}

// ---------------- mega: transform+transpose+store + fused loss, half-row blocks ----------------
__global__ __launch_bounds__(128, 6) void mega_kernel(
        const float* __restrict__ x, const float* __restrict__ iou,
        const void* __restrict__ om, const void* __restrict__ nm,
        const float* __restrict__ tw, const float* __restrict__ th,
        const float* __restrict__ tcls, const float* __restrict__ tconf,
        const float* __restrict__ tbox, const unsigned int* __restrict__ flags,
        float* __restrict__ out, float* __restrict__ partials){
    __shared__ __align__(16) float lt[FPB];     // transposed, transformed tile [38 cells][85 ch]
    __shared__ float raww[2][CELLS_PB];         // raw pw, ph

    const int tid = (int)threadIdx.x;
    // XCD swizzle: 7296 % 8 == 0 -> simple chunked bijection
    int blk = ((int)blockIdx.x & 7)*(NBLKM/8) + ((int)blockIdx.x >> 3);
    int ba = blk / HR_;
    int rr = blk - ba*HR_;
    int i  = rr >> 1;
    int h  = rr & 1;                 // half index
    int a  = ba % A_;
    float aw8 = (a==0)?12.0f:((a==1)?19.0f:40.0f);
    float ah8 = (a==0)?16.0f:((a==1)?36.0f:28.0f);
    float fi = (float)i;
    int col0 = h*CELLS_PB;           // first global column of this half-row
    const float* base = x + (size_t)ba*C_*GG_ + (size_t)i*G_ + col0;

    // ---- phase 1: coalesced float2 loads -> transform -> transposed LDS writes ----
    #pragma unroll
    for (int u=0;u<NITM;u++){
        int idx = tid + u*128;
        if (idx < NU2){
            int k  = idx/19;             // channel
            int j2 = idx - k*19;         // float2 index within half-row
            f2 v = *(const f2*)(base + (size_t)k*GG_ + j2*2);
            int m0 = j2*2;               // local cell
            float e0=v[0], e1=v[1];
            float r0,r1;
            if (k >= 4){
                r0 = sigf(e0); r1 = sigf(e1);
            } else if (k == 0){
                r0 = (sigf(e0)+(float)(col0+m0))*8.0f;
                r1 = (sigf(e1)+(float)(col0+m0+1))*8.0f;
            } else if (k == 1){
                r0 = (sigf(e0)+fi)*8.0f; r1 = (sigf(e1)+fi)*8.0f;
            } else if (k == 2){
                r0 = __expf(e0)*aw8; r1 = __expf(e1)*aw8;
                raww[0][m0] = e0; raww[0][m0+1] = e1;
            } else {
                r0 = __expf(e0)*ah8; r1 = __expf(e1)*ah8;
                raww[1][m0] = e0; raww[1][m0+1] = e1;
            }
            lt[m0*C_ + k]     = r0;
            lt[(m0+1)*C_ + k] = r1;
        }
    }
    __syncthreads();

    // ---- phase 2: contiguous float2 stores from LDS ----
    {
        float* dst = out + (size_t)blk*FPB;
        #pragma unroll
        for (int u=0;u<NITM;u++){
            int idx = tid + u*128;
            if (idx < NU2){
                int e0 = idx*2;
                f2 w = *(const f2*)(lt + e0);
                *(f2*)(dst + e0) = w;
            }
        }
    }

    // ---- phase 3: loss for 38 cells (wave 0, lanes 0..37) ----
    if (tid < 64){
        bool act = tid < CELLS_PB;
        int m = tid;
        size_t n = (size_t)ba*GG_ + (size_t)i*G_ + (size_t)(col0 + m);
        int mode = (flags[0]==0u) ? 0 : ((flags[1]==0u) ? 1 : 2);
        bool obj=false, noobj=false;
        float s0=0.f, s1=0.f, s2=0.f, s3=0.f;
        if (act){
            if (mode == 2){
                obj   = ((const unsigned char*)om)[n] != 0;
                noobj = ((const unsigned char*)nm)[n] != 0;
            } else {
                obj   = ((const unsigned int*)om)[n] != 0u;
                noobj = ((const unsigned int*)nm)[n] != 0u;
            }
        }
        if (act && (obj || noobj)){
            float pconf = lt[m*C_ + 4];
            float bc = bcef(pconf, tconf[n]);
            if (noobj) s2 = bc;
            if (obj){
                s1 = bc;
                float bx = lt[m*C_+0]*0.125f;
                float by = lt[m*C_+1]*0.125f;
                float bw = lt[m*C_+2]*0.125f;
                float bh = lt[m*C_+3]*0.125f;
                float pwv = raww[0][m], phv = raww[1][m];
                f4 tb = *(const f4*)(tbox + n*4);
                float txc=tb[0], tyc=tb[1], twd=tb[2], tht=tb[3];
                float tx1 = txc - twd*0.5f, ty1 = tyc - tht*0.5f;
                float tx2 = txc + twd*0.5f, ty2 = tyc + tht*0.5f;
                float px1 = bx - bw*0.5f,  py1 = by - bh*0.5f;
                float px2 = bx + bw*0.5f,  py2 = by + bh*0.5f;
                float xc1 = fminf(px1, tx1), yc1 = fminf(py1, ty1);
                float xc2 = fmaxf(px2, tx2), yc2 = fmaxf(py2, ty2);
                float cc = (xc2-xc1)*(xc2-xc1) + (yc2-yc1)*(yc2-yc1) + 1e-7f;
                float dd = (txc-bx)*(txc-bx) + (tyc-by)*(tyc-by);
                float rdiou = dd/cc;
                float dat = atanf(tw[n]/th[n]) - atanf(pwv/phv);
                float vv = 0.40528473456935108577f * dat*dat;
                float Si = 1.0f - iou[n];
                float alpha = vv/(Si+vv);
                s0 = 1.0f - iou[n] + rdiou + alpha*vv;
                const float* tcl = tcls + n*NC_;
                float cls = 0.f;
                #pragma unroll 4
                for (int c=0;c<NC_;c++)
                    cls += bcef(lt[m*C_+5+c], tcl[c]);
                s3 = cls;
            }
        }
        // intra-wave reduction (wave 0 only) -> direct partials write
        unsigned long long bo  = __ballot(act && obj);
        unsigned long long bn2 = __ballot(act && noobj);
        float vals[4] = {s0, s1, s2, s3};
        #pragma unroll
        for (int q=0;q<4;q++){
            float vv2 = vals[q];
            #pragma unroll
            for (int o=32;o>0;o>>=1) vv2 += __shfl_xor(vv2, o, 64);
            vals[q] = vv2;
        }
        if (tid == 0){
            partials[(size_t)0*NBLKM + blk] = vals[0];
            partials[(size_t)1*NBLKM + blk] = vals[1];
            partials[(size_t)2*NBLKM + blk] = vals[2];
            partials[(size_t)3*NBLKM + blk] = vals[3];
            partials[(size_t)4*NBLKM + blk] = (float)__popcll(bo);
            partials[(size_t)5*NBLKM + blk] = (float)__popcll(bn2);
        }
    }
}

// ---------------- final reduction ----------------
__global__ __launch_bounds__(256) void final_kernel(const float* __restrict__ partials,
                                                    float* __restrict__ out_loss){
    double acc[6] = {0,0,0,0,0,0};
    for (int idx = (int)threadIdx.x; idx < NBLKM; idx += 256){
        #pragma unroll
        for (int q=0;q<6;q++) acc[q] += (double)partials[(size_t)q*NBLKM + idx];
    }
    #pragma unroll
    for (int q=0;q<6;q++){
        double v = acc[q];
        #pragma unroll
        for (int o=32;o>0;o>>=1) v += __shfl_xor(v, o, 64);
        acc[q] = v;
    }
    __shared__ double smd[6][4];
    int lane = (int)threadIdx.x & 63, wid = (int)threadIdx.x >> 6;
    if (lane == 0){
        #pragma unroll
        for (int q=0;q<6;q++) smd[q][wid] = acc[q];
    }
    __syncthreads();
    if (threadIdx.x == 0){
        double s[6];
        #pragma unroll
        for (int q=0;q<6;q++) s[q] = smd[q][0]+smd[q][1]+smd[q][2]+smd[q][3];
        double cnt_o = fmax(s[4], 1.0);
        double cnt_n = fmax(s[5], 1.0);
        double total = s[0]/(double)B_
                     + s[1]/cnt_o
                     + 100.0*s[2]/cnt_n
                     + s[3]/(cnt_o*(double)NC_);
        *out_loss = (float)total;
    }
}

extern "C" void kernel_launch(void* const* d_in, const int* in_sizes, int n_in,
                              void* d_out, int out_size, void* d_ws, size_t ws_size,
                              hipStream_t stream){
    const float* x     = (const float*)d_in[0];
    const float* iou   = (const float*)d_in[1];
    const void*  om    = d_in[2];
    const void*  nm    = d_in[3];
    const float* tw    = (const float*)d_in[4];
    const float* th    = (const float*)d_in[5];
    const float* tcls  = (const float*)d_in[6];
    const float* tconf = (const float*)d_in[7];
    const float* tbox  = (const float*)d_in[8];
    float* out = (float*)d_out;

    unsigned int* flags = (unsigned int*)d_ws;
    float* partials = (float*)((char*)d_ws + 64);

    hipMemsetAsync(d_ws, 0, 64, stream);
    detect_kernel<<<1, 256, 0, stream>>>((const unsigned int*)nm, flags);
    mega_kernel<<<NBLKM, 128, 0, stream>>>(x, iou, om, nm, tw, th, tcls, tconf, tbox,
                                           flags, out, partials);
    final_kernel<<<1, 256, 0, stream>>>(partials, out + OUTN);
}

// Round 9
// 57.563 us; speedup vs baseline: 2.2907x; 1.4112x over previous
//
#include <hip/hip_runtime.h>

#define B_ 16
#define A_ 3
#define G_ 76
#define GG_ (G_*G_)             // 5776
#define NC_ 80
#define C_ 85
#define NCELL (B_*A_*GG_)       // 277248
#define OUTN ((size_t)NCELL*C_) // 23566080
#define NBLKM (NCELL/64)        // 4332 blocks, 64 cells each
#define LROW 88                 // padded LDS row (floats), %4==0 for b128 alignment

typedef float f4 __attribute__((ext_vector_type(4)));

__device__ __forceinline__ float sigf(float v){ return 1.0f/(1.0f + __expf(-v)); }
__device__ __forceinline__ float clog_(float p){ return fmaxf(__logf(p), -100.0f); }
__device__ __forceinline__ float bcef(float p, float t){ return -(t*clog_(p) + (1.0f-t)*clog_(1.0f-p)); }

// ---------------- mask dtype detection (1 block; noobj ~95% dense) ----------------
__global__ __launch_bounds__(256) void detect_kernel(const unsigned int* __restrict__ nm,
                                                     unsigned int* __restrict__ flags){
    unsigned v = nm[threadIdx.x];
    unsigned a01 = (v > 1u) ? 1u : 0u;                            // not int32 {0,1}
    unsigned afl = ((v != 0u) && (v != 0x3F800000u)) ? 1u : 0u;   // not f32 {0,1.0}
    if (__any(a01) && (threadIdx.x & 63) == 0) atomicOr(&flags[0], 1u);
    if (__any(afl) && (threadIdx.x & 63) == 0) atomicOr(&flags[1], 1u);
}

// ---------------- mega: wave-private transpose + transform + fused loss ----------------
// Block = 64 cells (4 waves x 16 cells). Wave lanes: kg=lane>>4 (channel group), ci=lane&15 (cell).
__global__ __launch_bounds__(256, 4) void mega_kernel(
        const float* __restrict__ x, const float* __restrict__ iou,
        const void* __restrict__ om, const void* __restrict__ nm,
        const float* __restrict__ tw, const float* __restrict__ th,
        const float* __restrict__ tcls, const float* __restrict__ tconf,
        const float* __restrict__ tbox, const unsigned int* __restrict__ flags,
        float* __restrict__ out, float* __restrict__ partials){
    __shared__ __align__(16) float lds[4][16*LROW];   // wave-private patches
    __shared__ float sred[4][6];

    const int tid  = (int)threadIdx.x;
    const int w    = tid >> 6;
    const int lane = tid & 63;
    const int kg   = lane >> 4;
    const int ci   = lane & 15;

    // bijective XCD-chunked swizzle (4332 = 4*542 + 4*541)
    unsigned qq = NBLKM >> 3, rr = NBLKM & 7u;
    unsigned xcd = blockIdx.x & 7u, seq = blockIdx.x >> 3;
    int blk = (int)((xcd < rr ? xcd*(qq+1u) : rr*(qq+1u) + (xcd-rr)*qq) + seq);

    int n0 = blk*64 + w*16;          // wave's first cell
    int n  = n0 + ci;                // lane's cell
    int ba = n / GG_;
    int ij = n - ba*GG_;
    int a  = ba % A_;
    int in_ = ij / G_;
    int jn  = ij - in_*G_;
    const float* xb = x + (size_t)ba*C_*GG_ + (size_t)ij;
    float* ldsw = lds[w];

    int mode = (flags[0]==0u) ? 0 : ((flags[1]==0u) ? 1 : 2);
    bool obj, noobj;
    if (mode == 2){
        obj   = ((const unsigned char*)om)[n] != 0;
        noobj = ((const unsigned char*)nm)[n] != 0;
    } else {
        obj   = ((const unsigned int*)om)[n] != 0u;   // int32 {0,1} or f32 {0,1.0f} bitpattern
        noobj = ((const unsigned int*)nm)[n] != 0u;
    }

    const float* tcl = tcls + (size_t)n*NC_;
    float aw8 = (a==0)?12.0f:((a==1)?19.0f:40.0f);
    float ah8 = (a==0)?16.0f:((a==1)?36.0f:28.0f);

    float clsacc = 0.f;
    float pb0=0.f, pb1=0.f, pb2=0.f, pb3=0.f, rwv=0.f, rhv=0.f, pcf=0.f;

    // ---- phase A: load 4-channel groups, transform, cls-BCE from regs, ds_write_b128 ----
    const float* p = xb + (size_t)(4*kg)*GG_;
    #pragma unroll
    for (int it=0; it<5; ++it){
        float e0 = p[0];
        float e1 = p[(size_t)GG_];
        float e2 = p[(size_t)2*GG_];
        float e3 = p[(size_t)3*GG_];
        int kb = 16*it + 4*kg;
        float r0,r1,r2,r3;
        if (it==0 && kg==0){
            float s0 = sigf(e0), s1 = sigf(e1);
            r0 = (s0 + (float)jn)*8.0f;
            r1 = (s1 + (float)in_)*8.0f;
            r2 = __expf(e2)*aw8;
            r3 = __expf(e3)*ah8;
            pb0=r0; pb1=r1; pb2=r2; pb3=r3; rwv=e2; rhv=e3;
        } else {
            r0 = sigf(e0); r1 = sigf(e1); r2 = sigf(e2); r3 = sigf(e3);
            if (it==0 && kg==1) pcf = r0;
            if (obj){
                if (kb+0 >= 5) clsacc += bcef(r0, tcl[kb-5]);
                if (kb+1 >= 5) clsacc += bcef(r1, tcl[kb-4]);
                if (kb+2 >= 5) clsacc += bcef(r2, tcl[kb-3]);
                if (kb+3 >= 5) clsacc += bcef(r3, tcl[kb-2]);
            }
        }
        f4 wv = {r0, r1, r2, r3};
        *(f4*)&ldsw[ci*LROW + kb] = wv;
        p += (size_t)16*GG_;
    }
    // tail: channels 80..84 (kg0: 80-83, kg1: 84; kg2/3 idle — no OOB loads)
    if (kg == 0){
        float e0=p[0], e1=p[(size_t)GG_], e2=p[(size_t)2*GG_], e3=p[(size_t)3*GG_];
        float q0=sigf(e0), q1=sigf(e1), q2=sigf(e2), q3=sigf(e3);
        f4 wv = {q0,q1,q2,q3};
        *(f4*)&ldsw[ci*LROW + 80] = wv;
        if (obj) clsacc += bcef(q0,tcl[75]) + bcef(q1,tcl[76]) + bcef(q2,tcl[77]) + bcef(q3,tcl[78]);
    } else if (kg == 1){
        float e4 = p[0];
        float q4 = sigf(e4);
        ldsw[ci*LROW + 84] = q4;
        if (obj) clsacc += bcef(q4, tcl[79]);
    }

    // ---- phase B: wave-private LDS -> aligned coalesced float4 stores (no barrier) ----
    {
        float* outw = out + (size_t)n0*C_;      // 5440B chunk, 16B-aligned
        #pragma unroll
        for (int itb=0; itb<6; ++itb){
            int f = lane + itb*64;
            if (f < 340){
                int e = f*4;
                int c = e/85;
                int k = e - c*85;
                int bix = c*LROW + k;
                float v0 = ldsw[bix];
                float v1 = ldsw[bix+1 + ((k+1>=85)?(LROW-85):0)];
                float v2 = ldsw[bix+2 + ((k+2>=85)?(LROW-85):0)];
                float v3 = ldsw[bix+3 + ((k+3>=85)?(LROW-85):0)];
                f4 sv = {v0,v1,v2,v3};
                ((f4*)outw)[f] = sv;
            }
        }
    }

    // ---- loss epilogue (registers only + tiny loads) ----
    float ciou=0.f, co=0.f, cn=0.f;
    if (kg==0 && obj){
        float iouv = iou[n], twv = tw[n], thv = th[n];
        f4 tb = *(const f4*)(tbox + (size_t)n*4);
        float bx = pb0*0.125f, by = pb1*0.125f, bw = pb2*0.125f, bh = pb3*0.125f;
        float txc=tb[0], tyc=tb[1], twd=tb[2], tht=tb[3];
        float tx1 = txc - twd*0.5f, ty1 = tyc - tht*0.5f;
        float tx2 = txc + twd*0.5f, ty2 = tyc + tht*0.5f;
        float px1 = bx - bw*0.5f,  py1 = by - bh*0.5f;
        float px2 = bx + bw*0.5f,  py2 = by + bh*0.5f;
        float xc1 = fminf(px1, tx1), yc1 = fminf(py1, ty1);
        float xc2 = fmaxf(px2, tx2), yc2 = fmaxf(py2, ty2);
        float cc = (xc2-xc1)*(xc2-xc1) + (yc2-yc1)*(yc2-yc1) + 1e-7f;
        float dd = (txc-bx)*(txc-bx) + (tyc-by)*(tyc-by);
        float rdiou = dd/cc;
        float dat = atanf(twv/thv) - atanf(rwv/rhv);
        float vv = 0.40528473456935108577f * dat*dat;
        float Si = 1.0f - iouv;
        float alpha = vv/(Si+vv);
        ciou = 1.0f - iouv + rdiou + alpha*vv;
    }
    if (kg==1 && (obj || noobj)){
        float bc = bcef(pcf, tconf[n]);
        co = obj ? bc : 0.f;
        cn = noobj ? bc : 0.f;
    }
    unsigned long long bo  = __ballot(obj)   & 0x00000000FFFF0000ULL;  // kg==1 lanes only
    unsigned long long bn2 = __ballot(noobj) & 0x00000000FFFF0000ULL;

    float vals[4] = {ciou, co, cn, clsacc};
    #pragma unroll
    for (int q2=0; q2<4; ++q2){
        float v = vals[q2];
        #pragma unroll
        for (int o=32; o>0; o>>=1) v += __shfl_xor(v, o, 64);
        vals[q2] = v;
    }
    if (lane == 0){
        sred[w][0]=vals[0]; sred[w][1]=vals[1]; sred[w][2]=vals[2]; sred[w][3]=vals[3];
        sred[w][4]=(float)__popcll(bo); sred[w][5]=(float)__popcll(bn2);
    }
    __syncthreads();
    if (tid < 6)
        partials[(size_t)tid*NBLKM + blk] = sred[0][tid]+sred[1][tid]+sred[2][tid]+sred[3][tid];
}

// ---------------- final reduction ----------------
__global__ __launch_bounds__(256) void final_kernel(const float* __restrict__ partials,
                                                    float* __restrict__ out_loss){
    double acc[6] = {0,0,0,0,0,0};
    for (int idx = (int)threadIdx.x; idx < NBLKM; idx += 256){
        #pragma unroll
        for (int q=0;q<6;q++) acc[q] += (double)partials[(size_t)q*NBLKM + idx];
    }
    #pragma unroll
    for (int q=0;q<6;q++){
        double v = acc[q];
        #pragma unroll
        for (int o=32;o>0;o>>=1) v += __shfl_xor(v, o, 64);
        acc[q] = v;
    }
    __shared__ double smd[6][4];
    int lane = (int)threadIdx.x & 63, wid = (int)threadIdx.x >> 6;
    if (lane == 0){
        #pragma unroll
        for (int q=0;q<6;q++) smd[q][wid] = acc[q];
    }
    __syncthreads();
    if (threadIdx.x == 0){
        double s[6];
        #pragma unroll
        for (int q=0;q<6;q++) s[q] = smd[q][0]+smd[q][1]+smd[q][2]+smd[q][3];
        double cnt_o = fmax(s[4], 1.0);
        double cnt_n = fmax(s[5], 1.0);
        double total = s[0]/(double)B_
                     + s[1]/cnt_o
                     + 100.0*s[2]/cnt_n
                     + s[3]/(cnt_o*(double)NC_);
        *out_loss = (float)total;
    }
}

extern "C" void kernel_launch(void* const* d_in, const int* in_sizes, int n_in,
                              void* d_out, int out_size, void* d_ws, size_t ws_size,
                              hipStream_t stream){
    const float* x     = (const float*)d_in[0];
    const float* iou   = (const float*)d_in[1];
    const void*  om    = d_in[2];
    const void*  nm    = d_in[3];
    const float* tw    = (const float*)d_in[4];
    const float* th    = (const float*)d_in[5];
    const float* tcls  = (const float*)d_in[6];
    const float* tconf = (const float*)d_in[7];
    const float* tbox  = (const float*)d_in[8];
    float* out = (float*)d_out;

    unsigned int* flags = (unsigned int*)d_ws;
    float* partials = (float*)((char*)d_ws + 64);

    hipMemsetAsync(d_ws, 0, 64, stream);
    detect_kernel<<<1, 256, 0, stream>>>((const unsigned int*)nm, flags);
    mega_kernel<<<NBLKM, 256, 0, stream>>>(x, iou, om, nm, tw, th, tcls, tconf, tbox,
                                           flags, out, partials);
    final_kernel<<<1, 256, 0, stream>>>(partials, out + OUTN);
}

// Round 10
// 48.888 us; speedup vs baseline: 2.6971x; 1.1774x over previous
//
#include <hip/hip_runtime.h>

#define B_ 16
#define A_ 3
#define G_ 76
#define GG_ (G_*G_)             // 5776
#define NC_ 80
#define C_ 85
#define NCELL (B_*A_*GG_)       // 277248
#define OUTN ((size_t)NCELL*C_) // 23566080
#define NBLKM (NCELL/64)        // 4332 blocks, 64 cells each

typedef float f4 __attribute__((ext_vector_type(4)));

__device__ __forceinline__ float sigf(float v){ return 1.0f/(1.0f + __expf(-v)); }
__device__ __forceinline__ float clog_(float p){ return fmaxf(__logf(p), -100.0f); }
__device__ __forceinline__ float bcef(float p, float t){ return -(t*clog_(p) + (1.0f-t)*clog_(1.0f-p)); }

// ---------------- mega: wave-private transpose + transform + fused loss ----------------
// Block = 64 cells (4 waves x 16 cells). Wave lanes: kg=lane>>4 (channel group), ci=lane&15 (cell).
// Masks: 4-byte elements; (word != 0) is correct for both int32 {0,1} and f32 {0,1.0f}.
__global__ __launch_bounds__(256, 7) void mega_kernel(
        const float* __restrict__ x, const float* __restrict__ iou,
        const unsigned int* __restrict__ om, const unsigned int* __restrict__ nm,
        const float* __restrict__ tw, const float* __restrict__ th,
        const float* __restrict__ tcls, const float* __restrict__ tconf,
        const float* __restrict__ tbox,
        float* __restrict__ out, float* __restrict__ partials){
    __shared__ __align__(16) float lds[4][16*C_];   // wave-private patches, flat [cell][channel]
    __shared__ float sred[4][6];

    const int tid  = (int)threadIdx.x;
    const int w    = tid >> 6;
    const int lane = tid & 63;
    const int kg   = lane >> 4;
    const int ci   = lane & 15;

    // bijective XCD-chunked swizzle (NBLKM % 8 == 4)
    unsigned qq = NBLKM >> 3, rr = NBLKM & 7u;
    unsigned xcd = blockIdx.x & 7u, seq = blockIdx.x >> 3;
    int blk = (int)((xcd < rr ? xcd*(qq+1u) : rr*(qq+1u) + (xcd-rr)*qq) + seq);

    int n0 = blk*64 + w*16;          // wave's first cell
    int n  = n0 + ci;                // lane's cell
    int ba = n / GG_;
    int ij = n - ba*GG_;
    int a  = ba % A_;
    int in_ = ij / G_;
    int jn  = ij - in_*G_;
    const float* xb = x + (size_t)ba*C_*GG_ + (size_t)ij;
    float* ldsw = lds[w];

    bool obj   = om[n] != 0u;
    bool noobj = nm[n] != 0u;

    const float* tcl = tcls + (size_t)n*NC_;
    float aw8 = (a==0)?12.0f:((a==1)?19.0f:40.0f);
    float ah8 = (a==0)?16.0f:((a==1)?36.0f:28.0f);

    float clsacc = 0.f;
    float pb0=0.f, pb1=0.f, pb2=0.f, pb3=0.f, rwv=0.f, rhv=0.f, pcf=0.f;

    // ---- phase A: load 4-channel groups, transform, cls-BCE from regs, scalar ds_writes ----
    const float* p = xb + (size_t)(4*kg)*GG_;
    #pragma unroll
    for (int it=0; it<5; ++it){
        float e0 = p[0];
        float e1 = p[(size_t)GG_];
        float e2 = p[(size_t)2*GG_];
        float e3 = p[(size_t)3*GG_];
        int kb = 16*it + 4*kg;
        float r0,r1,r2,r3;
        if (it==0 && kg==0){
            float s0 = sigf(e0), s1 = sigf(e1);
            r0 = (s0 + (float)jn)*8.0f;
            r1 = (s1 + (float)in_)*8.0f;
            r2 = __expf(e2)*aw8;
            r3 = __expf(e3)*ah8;
            pb0=r0; pb1=r1; pb2=r2; pb3=r3; rwv=e2; rhv=e3;
        } else {
            r0 = sigf(e0); r1 = sigf(e1); r2 = sigf(e2); r3 = sigf(e3);
            if (it==0 && kg==1) pcf = r0;
            if (obj){
                if (kb+0 >= 5) clsacc += bcef(r0, tcl[kb-5]);
                if (kb+1 >= 5) clsacc += bcef(r1, tcl[kb-4]);
                if (kb+2 >= 5) clsacc += bcef(r2, tcl[kb-3]);
                if (kb+3 >= 5) clsacc += bcef(r3, tcl[kb-2]);
            }
        }
        int bix = ci*C_ + kb;
        ldsw[bix+0] = r0;
        ldsw[bix+1] = r1;
        ldsw[bix+2] = r2;
        ldsw[bix+3] = r3;
        p += (size_t)16*GG_;
    }
    // tail: channels 80..84 (kg0: 80-83, kg1: 84; kg2/3 idle — no OOB loads)
    if (kg == 0){
        float e0=p[0], e1=p[(size_t)GG_], e2=p[(size_t)2*GG_], e3=p[(size_t)3*GG_];
        float q0=sigf(e0), q1=sigf(e1), q2=sigf(e2), q3=sigf(e3);
        int bix = ci*C_ + 80;
        ldsw[bix+0]=q0; ldsw[bix+1]=q1; ldsw[bix+2]=q2; ldsw[bix+3]=q3;
        if (obj) clsacc += bcef(q0,tcl[75]) + bcef(q1,tcl[76]) + bcef(q2,tcl[77]) + bcef(q3,tcl[78]);
    } else if (kg == 1){
        float e4 = p[0];
        float q4 = sigf(e4);
        ldsw[ci*C_ + 84] = q4;
        if (obj) clsacc += bcef(q4, tcl[79]);
    }

    // ---- phase B: flat LDS -> aligned coalesced float4 stores (no barrier; wave-private) ----
    {
        float* outw = out + (size_t)n0*C_;      // 5440B chunk, 16B-aligned
        const f4* src4 = (const f4*)ldsw;       // 1360 floats = 340 f4, contiguous
        f4* dst4 = (f4*)outw;
        #pragma unroll
        for (int itb=0; itb<6; ++itb){
            int f = lane + itb*64;
            if (f < 340) dst4[f] = src4[f];
        }
    }

    // ---- loss epilogue (registers only + tiny loads) ----
    float ciou=0.f, co=0.f, cn=0.f;
    if (kg==0 && obj){
        float iouv = iou[n], twv = tw[n], thv = th[n];
        f4 tb = *(const f4*)(tbox + (size_t)n*4);
        float bx = pb0*0.125f, by = pb1*0.125f, bw = pb2*0.125f, bh = pb3*0.125f;
        float txc=tb[0], tyc=tb[1], twd=tb[2], tht=tb[3];
        float tx1 = txc - twd*0.5f, ty1 = tyc - tht*0.5f;
        float tx2 = txc + twd*0.5f, ty2 = tyc + tht*0.5f;
        float px1 = bx - bw*0.5f,  py1 = by - bh*0.5f;
        float px2 = bx + bw*0.5f,  py2 = by + bh*0.5f;
        float xc1 = fminf(px1, tx1), yc1 = fminf(py1, ty1);
        float xc2 = fmaxf(px2, tx2), yc2 = fmaxf(py2, ty2);
        float cc = (xc2-xc1)*(xc2-xc1) + (yc2-yc1)*(yc2-yc1) + 1e-7f;
        float dd = (txc-bx)*(txc-bx) + (tyc-by)*(tyc-by);
        float rdiou = dd/cc;
        float dat = atanf(twv/thv) - atanf(rwv/rhv);
        float vv = 0.40528473456935108577f * dat*dat;
        float Si = 1.0f - iouv;
        float alpha = vv/(Si+vv);
        ciou = 1.0f - iouv + rdiou + alpha*vv;
    }
    if (kg==1 && (obj || noobj)){
        float bc = bcef(pcf, tconf[n]);
        co = obj ? bc : 0.f;
        cn = noobj ? bc : 0.f;
    }
    unsigned long long bo  = __ballot(obj)   & 0x00000000FFFF0000ULL;  // kg==1 lanes only
    unsigned long long bn2 = __ballot(noobj) & 0x00000000FFFF0000ULL;

    float vals[4] = {ciou, co, cn, clsacc};
    #pragma unroll
    for (int q2=0; q2<4; ++q2){
        float v = vals[q2];
        #pragma unroll
        for (int o=32; o>0; o>>=1) v += __shfl_xor(v, o, 64);
        vals[q2] = v;
    }
    if (lane == 0){
        sred[w][0]=vals[0]; sred[w][1]=vals[1]; sred[w][2]=vals[2]; sred[w][3]=vals[3];
        sred[w][4]=(float)__popcll(bo); sred[w][5]=(float)__popcll(bn2);
    }
    __syncthreads();
    if (tid < 6)
        partials[(size_t)tid*NBLKM + blk] = sred[0][tid]+sred[1][tid]+sred[2][tid]+sred[3][tid];
}

// ---------------- final reduction ----------------
__global__ __launch_bounds__(256) void final_kernel(const float* __restrict__ partials,
                                                    float* __restrict__ out_loss){
    double acc[6] = {0,0,0,0,0,0};
    for (int idx = (int)threadIdx.x; idx < NBLKM; idx += 256){
        #pragma unroll
        for (int q=0;q<6;q++) acc[q] += (double)partials[(size_t)q*NBLKM + idx];
    }
    #pragma unroll
    for (int q=0;q<6;q++){
        double v = acc[q];
        #pragma unroll
        for (int o=32;o>0;o>>=1) v += __shfl_xor(v, o, 64);
        acc[q] = v;
    }
    __shared__ double smd[6][4];
    int lane = (int)threadIdx.x & 63, wid = (int)threadIdx.x >> 6;
    if (lane == 0){
        #pragma unroll
        for (int q=0;q<6;q++) smd[q][wid] = acc[q];
    }
    __syncthreads();
    if (threadIdx.x == 0){
        double s[6];
        #pragma unroll
        for (int q=0;q<6;q++) s[q] = smd[q][0]+smd[q][1]+smd[q][2]+smd[q][3];
        double cnt_o = fmax(s[4], 1.0);
        double cnt_n = fmax(s[5], 1.0);
        double total = s[0]/(double)B_
                     + s[1]/cnt_o
                     + 100.0*s[2]/cnt_n
                     + s[3]/(cnt_o*(double)NC_);
        *out_loss = (float)total;
    }
}

extern "C" void kernel_launch(void* const* d_in, const int* in_sizes, int n_in,
                              void* d_out, int out_size, void* d_ws, size_t ws_size,
                              hipStream_t stream){
    const float* x     = (const float*)d_in[0];
    const float* iou   = (const float*)d_in[1];
    const unsigned int* om = (const unsigned int*)d_in[2];
    const unsigned int* nm = (const unsigned int*)d_in[3];
    const float* tw    = (const float*)d_in[4];
    const float* th    = (const float*)d_in[5];
    const float* tcls  = (const float*)d_in[6];
    const float* tconf = (const float*)d_in[7];
    const float* tbox  = (const float*)d_in[8];
    float* out = (float*)d_out;

    float* partials = (float*)d_ws;

    mega_kernel<<<NBLKM, 256, 0, stream>>>(x, iou, om, nm, tw, th, tcls, tconf, tbox,
                                           out, partials);
    final_kernel<<<1, 256, 0, stream>>>(partials, out + OUTN);
}